// Round 14
// baseline (170.850 us; speedup 1.0000x reference)
//
#include <hip/hip_runtime.h>

// NeRF render, numerics contract (frozen from r8, PASSED):
//   sdt_i = fmul(sg, fsub(te,ts));  blocked-16 XLA cumsum:
//   s1[g] = within-16 fold of T0 (T0[g] = fold16 of sdt);  upper recursion
//   16384->1024->64->4 sequential folds + combine adds -> C2[16384];
//   C1[j] = (j>>4)? fadd(s1[j], C2[(j>>4)-1]) : s1[j];
//   C_i = g? fadd(fold16_incl(i), C1[g-1]) : fold16_incl(i);
//   excl_i = fsub(C_i, sdt_i);  expo = fsub(excl_i, el[ray]);
//   w = fmul(exp(-expo), fsub(1, exp(-sdt_i))).
// r22: delete the k_mid dispatch. total-minus-k_render is stable ~126us;
// k_mid (1 block, 1 CU busy, 2 launch gaps) is the last controllable chunk.
// Every k_render block now redundantly replicates k_mid's upper recursion
// from T1 in a prologue (256-thread port ALREADY VERIFIED in r9's fused
// kernel): level2 totals -> T2sh; level3/4/base/C4/C3 in LDS (verbatim
// chains); then 10 threads materialize the 9 C2 entries this block's cj
// can touch (m in [8b-2, 8b+6]), s2 folded on demand from L2-hot T1 with
// the exact contract chain. el_lead's arbitrary C2[m] computed on demand
// from s3sh (lane 0 only, rare). Redundant cost ~0.5us VALU + ~4us L2
// aggregate; LDS 8.7KB. 2 dispatches. k_bottom + r13 render body (store/
// atomic split, PASSED) byte-identical.

#define TPB 256
#define LDSF (256 * 17)      // k_bottom padded tile: 256 groups x 16 + pad

// update_dpp with old=0: masked/invalid lanes yield exactly 0.0f.
#define DPP0(SRC, CTRL, RMASK, BC) __int_as_float(__builtin_amdgcn_update_dpp( \
        0, __float_as_int(SRC), (CTRL), (RMASK), 0xf, (BC)))

// int max with DPP-shifted operand (old=0 identity for keys >= 0)
#define IMAXD(V, CTRL, RMASK, BC) { \
    int _tmp = __builtin_amdgcn_update_dpp(0, (V), (CTRL), (RMASK), 0xf, (BC)); \
    (V) = ((V) > _tmp) ? (V) : _tmp; }

#define ADD4(A, B) make_float4((A).x + (B).x, (A).y + (B).y, (A).z + (B).z, (A).w + (B).w)

// serial left-fold prefix within each 16-lane row, exact contract order.
__device__ __forceinline__ float fold16_dpp(float x) {
    float a = 0.0f;
    a = __fadd_rn(a, DPP0(x, 0x110 | 15, 0xf, true));
    a = __fadd_rn(a, DPP0(x, 0x110 | 14, 0xf, true));
    a = __fadd_rn(a, DPP0(x, 0x110 | 13, 0xf, true));
    a = __fadd_rn(a, DPP0(x, 0x110 | 12, 0xf, true));
    a = __fadd_rn(a, DPP0(x, 0x110 | 11, 0xf, true));
    a = __fadd_rn(a, DPP0(x, 0x110 | 10, 0xf, true));
    a = __fadd_rn(a, DPP0(x, 0x110 |  9, 0xf, true));
    a = __fadd_rn(a, DPP0(x, 0x110 |  8, 0xf, true));
    a = __fadd_rn(a, DPP0(x, 0x110 |  7, 0xf, true));
    a = __fadd_rn(a, DPP0(x, 0x110 |  6, 0xf, true));
    a = __fadd_rn(a, DPP0(x, 0x110 |  5, 0xf, true));
    a = __fadd_rn(a, DPP0(x, 0x110 |  4, 0xf, true));
    a = __fadd_rn(a, DPP0(x, 0x110 |  3, 0xf, true));
    a = __fadd_rn(a, DPP0(x, 0x110 |  2, 0xf, true));
    a = __fadd_rn(a, DPP0(x, 0x110 |  1, 0xf, true));
    a = __fadd_rn(a, x);
    return a;
}

// inclusive 64-lane scan (segment sums only; rounding-free path)
__device__ __forceinline__ float wscan(float v) {
    v = __fadd_rn(v, DPP0(v, 0x111, 0xf, true));   // row_shr:1
    v = __fadd_rn(v, DPP0(v, 0x112, 0xf, true));   // row_shr:2
    v = __fadd_rn(v, DPP0(v, 0x114, 0xf, true));   // row_shr:4
    v = __fadd_rn(v, DPP0(v, 0x118, 0xf, true));   // row_shr:8
    v = __fadd_rn(v, DPP0(v, 0x142, 0xa, false));  // row_bcast15 -> rows 1,3
    v = __fadd_rn(v, DPP0(v, 0x143, 0xc, false));  // row_bcast31 -> rows 2,3
    return v;
}

__device__ __forceinline__ float sdt_c(float tsv, float tev, float sgv) {
    return __fmul_rn(sgv, __fsub_rn(tev, tsv));
}

// block = one 4096-float tile: coalesced loads, sdt written coalesced,
// staged into padded LDS; thread t serially folds its 16-group from LDS.
__global__ void k_bottom(const float* __restrict__ ts, const float* __restrict__ te,
                         const float* __restrict__ sg, int S,
                         float* __restrict__ sdt, float* __restrict__ s1,
                         float* __restrict__ T1,
                         float4* __restrict__ out4, int n_rays) {
    __shared__ float lds[LDSF];
    int t = threadIdx.x;
    int tile = blockIdx.x;                    // grid = N1/TPB = 1024 tiles
    int gid = tile * TPB + t;
    if (gid < n_rays) out4[gid] = make_float4(0.f, 0.f, 0.f, 0.f);
    const float4* ts4 = (const float4*)ts;
    const float4* te4 = (const float4*)te;
    const float4* sg4 = (const float4*)sg;
    float4* sdt4 = (float4*)sdt;
    #pragma unroll
    for (int k = 0; k < 4; ++k) {
        int idx4 = tile * 1024 + k * 256 + t;  // lane-contiguous float4
        float4 a = ts4[idx4], b = te4[idx4], c = sg4[idx4];
        float4 xo;
        xo.x = sdt_c(a.x, b.x, c.x);
        xo.y = sdt_c(a.y, b.y, c.y);
        xo.z = sdt_c(a.z, b.z, c.z);
        xo.w = sdt_c(a.w, b.w, c.w);
        sdt4[idx4] = xo;                       // coalesced write
        int fl = (k * 256 + t) << 2;           // float idx within tile
        int g0 = fl >> 4, j0 = fl & 15;
        float* p = &lds[g0 * 17 + j0];
        p[0] = xo.x; p[1] = xo.y; p[2] = xo.z; p[3] = xo.w;
    }
    __syncthreads();
    float acc = 0.0f;
    #pragma unroll
    for (int j = 0; j < 16; ++j) acc = __fadd_rn(acc, lds[t * 17 + j]);
    float acc2 = fold16_dpp(acc);              // within-16 row fold -> s1
    int g = tile * 256 + t;
    s1[g] = acc2;
    if ((t & 15) == 15) T1[g >> 4] = acc2;
}

// wave-autonomous render, 8 samples/thread. Prologue: per-block redundant
// recompute of k_mid's upper recursion from T1 (exact chains, r9-verified
// 256-thread port); C2 entries needed by this block -> C2nd[10].
__global__ void k_render(const int* __restrict__ ri, const float* __restrict__ sdt,
                         const float* __restrict__ s1, const float* __restrict__ T1,
                         const float* __restrict__ hdr,
                         int S, float* __restrict__ out) {
    __shared__ float T2sh[1024];
    __shared__ float s3sh[1024];   // becomes C3 in place
    __shared__ float s4sh[64];     // becomes C4 in place
    __shared__ float T3sh[64];
    __shared__ float T4sh[4];
    __shared__ float C5sh[4];
    __shared__ float C2nd[10];
    const int tx = threadIdx.x;
    const float4* T14 = (const float4*)T1;

    // ---- prologue: upper recursion (totals-only level 2)
    #pragma unroll
    for (int q = 0; q < 4; ++q) {
        int grp = tx + 256 * q;
        float a2 = 0.0f;
        #pragma unroll
        for (int kk = 0; kk < 4; ++kk) {
            float4 v = T14[grp * 4 + kk];
            a2 = __fadd_rn(a2, v.x);
            a2 = __fadd_rn(a2, v.y);
            a2 = __fadd_rn(a2, v.z);
            a2 = __fadd_rn(a2, v.w);
        }
        T2sh[grp] = a2;
    }
    __syncthreads();
    if (tx < 64) {                 // level 3
        float a3 = 0.0f;
        for (int j = 0; j < 16; ++j) { a3 = __fadd_rn(a3, T2sh[tx * 16 + j]); s3sh[tx * 16 + j] = a3; }
        T3sh[tx] = a3;
    }
    __syncthreads();
    if (tx < 4) {                  // level 4
        float a4 = 0.0f;
        for (int j = 0; j < 16; ++j) { a4 = __fadd_rn(a4, T3sh[tx * 16 + j]); s4sh[tx * 16 + j] = a4; }
        T4sh[tx] = a4;
    }
    __syncthreads();
    if (tx == 0) {                 // base fold of 4
        float c = 0.0f;
        for (int r = 0; r < 4; ++r) { c = __fadd_rn(c, T4sh[r]); C5sh[r] = c; }
    }
    __syncthreads();
    if (tx < 64) {                 // C4 in place
        int r = tx >> 4;
        float v4 = s4sh[tx];
        s4sh[tx] = r ? __fadd_rn(v4, C5sh[r - 1]) : v4;
    }
    __syncthreads();
    for (int e = tx; e < 1024; e += 256) {   // C3 in place
        int r = e >> 4;
        float v3 = s3sh[e];
        s3sh[e] = r ? __fadd_rn(v3, s4sh[r - 1]) : v3;
    }
    __syncthreads();
    if (tx < 10) {                 // C2 entries this block can touch
        int m = blockIdx.x * 8 - 2 + tx;
        float c2v = 0.0f;
        if (m >= 0) {
            int grp = m >> 4, lm = m & 15;
            float4 q0 = T14[grp * 4 + 0], q1 = T14[grp * 4 + 1];
            float4 q2 = T14[grp * 4 + 2], q3 = T14[grp * 4 + 3];
            float vv[16] = { q0.x, q0.y, q0.z, q0.w, q1.x, q1.y, q1.z, q1.w,
                             q2.x, q2.y, q2.z, q2.w, q3.x, q3.y, q3.z, q3.w };
            float a2 = 0.0f;
            #pragma unroll
            for (int j2 = 0; j2 < 16; ++j2) {
                if (j2 <= lm) a2 = __fadd_rn(a2, vv[j2]);
            }
            c2v = grp ? __fadd_rn(a2, s3sh[grp - 1]) : a2;
        }
        C2nd[tx] = c2v;
    }
    __syncthreads();

    // ---- render body (r13, PASSED)
    const int tid = blockIdx.x * TPB + threadIdx.x;
    const int t = threadIdx.x & 63;           // lane
    const int i0 = tid * 8;                   // first sample of this thread
    const bool valid = i0 < S;

    float4 xa, xb; int4 ra, rb;
    if (valid) {
        xa = ((const float4*)sdt)[2 * tid];
        xb = ((const float4*)sdt)[2 * tid + 1];
        ra = ((const int4*)ri)[2 * tid];
        rb = ((const int4*)ri)[2 * tid + 1];
    } else {
        xa = xb = make_float4(0.f, 0.f, 0.f, 0.f);
        ra.x = ra.y = ra.z = ra.w = -1 - t;
        rb = ra;
    }

    int dpr = __builtin_amdgcn_update_dpp(0, rb.w, 0x111, 0xf, 0xf, true);
    int prev_r = dpr;
    if ((t & 15) == 0) prev_r = (i0 == 0 || !valid) ? (ra.x ^ 1) : ri[i0 - 1];

    bool f0 = prev_r != ra.x;
    bool f1 = ra.y != ra.x, f2 = ra.z != ra.y, f3 = ra.w != ra.z;
    bool f4 = rb.x != ra.w, f5 = rb.y != rb.x, f6 = rb.z != rb.y, f7 = rb.w != rb.z;
    unsigned long long mask0 = __ballot(f0);

    float p0 = __fadd_rn(0.0f, xa.x);
    float p1 = __fadd_rn(p0, xa.y);
    float p2 = __fadd_rn(p1, xa.z);
    float p3 = __fadd_rn(p2, xa.w);
    float p4 = __fadd_rn(p3, xb.x);
    float p5 = __fadd_rn(p4, xb.y);
    float p6 = __fadd_rn(p5, xb.z);
    float p7 = __fadd_rn(p6, xb.w);
    {
        float cin = DPP0(p7, 0x111, 0xf, true);   // lane-1's 8-total
        float n0 = __fadd_rn(cin, xa.x);
        float n1 = __fadd_rn(n0, xa.y);
        float n2 = __fadd_rn(n1, xa.z);
        float n3 = __fadd_rn(n2, xa.w);
        float n4 = __fadd_rn(n3, xb.x);
        float n5 = __fadd_rn(n4, xb.y);
        float n6 = __fadd_rn(n5, xb.z);
        float n7 = __fadd_rn(n6, xb.w);
        bool me = (t & 1) != 0;
        p0 = me ? n0 : p0; p1 = me ? n1 : p1;
        p2 = me ? n2 : p2; p3 = me ? n3 : p3;
        p4 = me ? n4 : p4; p5 = me ? n5 : p5;
        p6 = me ? n6 : p6; p7 = me ? n7 : p7;
    }

    int g = i0 >> 4;
    float cj = 0.0f;
    if (valid && g) {
        int j3 = g - 1;
        int m4 = j3 >> 4;
        // C2[m4-1] from the per-block C2nd cache: index = m4 + 1 - 8*blockIdx.x
        cj = m4 ? __fadd_rn(s1[j3], C2nd[m4 + 1 - blockIdx.x * 8]) : s1[j3];
    }
    float e0 = __fsub_rn(g ? __fadd_rn(p0, cj) : p0, xa.x);
    float e1 = __fsub_rn(g ? __fadd_rn(p1, cj) : p1, xa.y);
    float e2 = __fsub_rn(g ? __fadd_rn(p2, cj) : p2, xa.z);
    float e3 = __fsub_rn(g ? __fadd_rn(p3, cj) : p3, xa.w);
    float e4 = __fsub_rn(g ? __fadd_rn(p4, cj) : p4, xb.x);
    float e5 = __fsub_rn(g ? __fadd_rn(p5, cj) : p5, xb.y);
    float e6 = __fsub_rn(g ? __fadd_rn(p6, cj) : p6, xb.z);
    float e7 = __fsub_rn(g ? __fadd_rn(p7, cj) : p7, xb.w);

    // ---- el for the wave-leading run (head in an earlier wave)
    float el_lead = 0.0f;
    if (!(mask0 & 1ull)) {                    // wave-uniform branch
        int wbs = (tid - t) * 8;              // wave's first sample
        int r0v = __builtin_amdgcn_readfirstlane(ra.x);
        int h0 = 0;
        for (int round = 0; round < 65536; ++round) {
            int idx = wbs - 1 - t - 64 * round;
            int rv = (idx >= 0) ? ri[idx] : (r0v ^ 1);
            unsigned long long mm = __ballot(rv != r0v);
            if (mm) {
                int lm = __ffsll((unsigned long long)mm) - 1;
                h0 = wbs - 64 * round - lm;
                break;
            }
        }
        float elv = 0.0f;
        if (t == 0) {                         // recompute C_head, frozen fold
            const float4* s4 = (const float4*)sdt;
            int gh = h0 >> 4, lh = h0 & 15;
            float4 q0 = s4[gh * 4 + 0], q1 = s4[gh * 4 + 1];
            float4 q2 = s4[gh * 4 + 2], q3 = s4[gh * 4 + 3];
            float vv[16] = { q0.x, q0.y, q0.z, q0.w, q1.x, q1.y, q1.z, q1.w,
                             q2.x, q2.y, q2.z, q2.w, q3.x, q3.y, q3.z, q3.w };
            float a2 = 0.0f, xl = 0.0f;
            #pragma unroll
            for (int j2 = 0; j2 < 16; ++j2) {
                if (j2 <= lh) { a2 = __fadd_rn(a2, vv[j2]); xl = vv[j2]; }
            }
            float Ch = a2;
            if (gh) {
                int j3b = gh - 1;
                int mb = j3b >> 4;
                float cjb;
                if (mb) {
                    // on-demand C2[mb-1] = s2 fold (exact chain) + C3 (LDS)
                    int m = mb - 1;
                    int grp2 = m >> 4, lm2 = m & 15;
                    float4 u0 = T14[grp2 * 4 + 0], u1 = T14[grp2 * 4 + 1];
                    float4 u2 = T14[grp2 * 4 + 2], u3 = T14[grp2 * 4 + 3];
                    float uu[16] = { u0.x, u0.y, u0.z, u0.w, u1.x, u1.y, u1.z, u1.w,
                                     u2.x, u2.y, u2.z, u2.w, u3.x, u3.y, u3.z, u3.w };
                    float s2v = 0.0f;
                    #pragma unroll
                    for (int j2 = 0; j2 < 16; ++j2) {
                        if (j2 <= lm2) s2v = __fadd_rn(s2v, uu[j2]);
                    }
                    float c2v = grp2 ? __fadd_rn(s2v, s3sh[grp2 - 1]) : s2v;
                    cjb = __fadd_rn(s1[j3b], c2v);
                } else {
                    cjb = s1[j3b];
                }
                Ch = __fadd_rn(a2, cjb);
            }
            elv = __fsub_rn(Ch, xl);
        }
        el_lead = __int_as_float(__builtin_amdgcn_readfirstlane(__float_as_int(elv)));
    }

    // ---- head-before flags
    bool hb0 = f0, hb1 = f1 | hb0, hb2 = f2 | hb1, hb3 = f3 | hb2;
    bool hb4 = f4 | hb3, hb5 = f5 | hb4, hb6 = f6 | hb5, hb7 = f7 | hb6;

    // ---- cross-lane source: last lane < me that contains a head
    int key = (valid && hb7) ? (t + 1) : 0;
    int sk = __shfl_up(key, 1, 64);
    if (t == 0) sk = 0;
    int M = sk;
    IMAXD(M, 0x111, 0xf, true)
    IMAXD(M, 0x112, 0xf, true)
    IMAXD(M, 0x114, 0xf, true)
    IMAXD(M, 0x118, 0xf, true)
    IMAXD(M, 0x142, 0xa, false)
    IMAXD(M, 0x143, 0xc, false)
    int src = M;
    int psrc = (src > 0) ? (src - 1) : t;

    float el7c = f7 ? e7 : f6 ? e6 : f5 ? e5 : f4 ? e4 :
                 f3 ? e3 : f2 ? e2 : f1 ? e1 : f0 ? e0 : 0.0f;
    float rel = __shfl(el7c, psrc, 64);
    float el_prev = (src > 0) ? rel : el_lead;

    float el0 = f0 ? e0 : el_prev;
    float el1 = f1 ? e1 : el0;
    float el2 = f2 ? e2 : el1;
    float el3 = f3 ? e3 : el2;
    float el4 = f4 ? e4 : el3;
    float el5 = f5 ? e5 : el4;
    float el6 = f6 ? e6 : el5;
    float el7 = f7 ? e7 : el6;

    // ---- weights + hdr (direct float4 loads, as r7/r10)
    float4 h0v, h1v, h2v, h3v, h4v, h5v;
    if (valid) {
        const float4* h4 = (const float4*)hdr;
        h0v = h4[6 * tid + 0]; h1v = h4[6 * tid + 1]; h2v = h4[6 * tid + 2];
        h3v = h4[6 * tid + 3]; h4v = h4[6 * tid + 4]; h5v = h4[6 * tid + 5];
    } else {
        h0v = h1v = h2v = h3v = h4v = h5v = make_float4(0.f, 0.f, 0.f, 0.f);
    }
    float w0 = 0.f, w1 = 0.f, w2 = 0.f, w3 = 0.f;
    float w4 = 0.f, w5 = 0.f, w6 = 0.f, w7 = 0.f;
    if (valid) {
        w0 = __fmul_rn(__expf(-__fsub_rn(e0, el0)), __fsub_rn(1.0f, __expf(-xa.x)));
        w1 = __fmul_rn(__expf(-__fsub_rn(e1, el1)), __fsub_rn(1.0f, __expf(-xa.y)));
        w2 = __fmul_rn(__expf(-__fsub_rn(e2, el2)), __fsub_rn(1.0f, __expf(-xa.z)));
        w3 = __fmul_rn(__expf(-__fsub_rn(e3, el3)), __fsub_rn(1.0f, __expf(-xa.w)));
        w4 = __fmul_rn(__expf(-__fsub_rn(e4, el4)), __fsub_rn(1.0f, __expf(-xb.x)));
        w5 = __fmul_rn(__expf(-__fsub_rn(e5, el5)), __fsub_rn(1.0f, __expf(-xb.y)));
        w6 = __fmul_rn(__expf(-__fsub_rn(e6, el6)), __fsub_rn(1.0f, __expf(-xb.z)));
        w7 = __fmul_rn(__expf(-__fsub_rn(e7, el7)), __fsub_rn(1.0f, __expf(-xb.w)));
    }
    float4 v0 = make_float4(w0, __fmul_rn(w0, h0v.x), __fmul_rn(w0, h0v.y), __fmul_rn(w0, h0v.z));
    float4 v1 = make_float4(w1, __fmul_rn(w1, h0v.w), __fmul_rn(w1, h1v.x), __fmul_rn(w1, h1v.y));
    float4 v2 = make_float4(w2, __fmul_rn(w2, h1v.z), __fmul_rn(w2, h1v.w), __fmul_rn(w2, h2v.x));
    float4 v3 = make_float4(w3, __fmul_rn(w3, h2v.y), __fmul_rn(w3, h2v.z), __fmul_rn(w3, h2v.w));
    float4 v4 = make_float4(w4, __fmul_rn(w4, h3v.x), __fmul_rn(w4, h3v.y), __fmul_rn(w4, h3v.z));
    float4 v5 = make_float4(w5, __fmul_rn(w5, h3v.w), __fmul_rn(w5, h4v.x), __fmul_rn(w5, h4v.y));
    float4 v6 = make_float4(w6, __fmul_rn(w6, h4v.z), __fmul_rn(w6, h4v.w), __fmul_rn(w6, h5v.x));
    float4 v7 = make_float4(w7, __fmul_rn(w7, h5v.y), __fmul_rn(w7, h5v.z), __fmul_rn(w7, h5v.w));

    float4 V0 = v0;
    float4 V1 = ADD4(V0, v1);
    float4 V2 = ADD4(V1, v2);
    float4 V3 = ADD4(V2, v3);
    float4 V4 = ADD4(V3, v4);
    float4 V5 = ADD4(V4, v5);
    float4 V6 = ADD4(V5, v6);
    float4 V7 = ADD4(V6, v7);

    float4 W;
    W.x = wscan(V7.x); W.y = wscan(V7.y); W.z = wscan(V7.z); W.w = wscan(V7.w);
    float4 E;
    E.x = __shfl_up(W.x, 1, 64);
    E.y = __shfl_up(W.y, 1, 64);
    E.z = __shfl_up(W.z, 1, 64);
    E.w = __shfl_up(W.w, 1, 64);
    if (t == 0) { E.x = 0.f; E.y = 0.f; E.z = 0.f; E.w = 0.f; }

    float4 Z = make_float4(0.f, 0.f, 0.f, 0.f);
    float4 B0 = f0 ? E : Z;
    float4 B1 = f1 ? ADD4(E, V0) : B0;
    float4 B2 = f2 ? ADD4(E, V1) : B1;
    float4 B3 = f3 ? ADD4(E, V2) : B2;
    float4 B4 = f4 ? ADD4(E, V3) : B3;
    float4 B5 = f5 ? ADD4(E, V4) : B4;
    float4 B6 = f6 ? ADD4(E, V5) : B5;
    float4 B7 = f7 ? ADD4(E, V6) : B6;

    float4 rbs;
    rbs.x = __shfl(B7.x, psrc, 64);
    rbs.y = __shfl(B7.y, psrc, 64);
    rbs.z = __shfl(B7.z, psrc, 64);
    rbs.w = __shfl(B7.w, psrc, 64);
    float4 bs_prev = (src > 0) ? rbs : Z;

    bool tl0 = f1, tl1 = f2, tl2 = f3, tl3 = f4, tl4 = f5, tl5 = f6, tl6 = f7;
    bool tl7 = (t < 63) ? (((mask0 >> (t + 1)) & 1ull) != 0ull) : true;
    bool rt7 = (t < 63);

#define EMIT(K, TLK, RJ, VK, RT) \
    if (valid && (TLK) && (RJ) >= 0) { \
        float4 bse = hb##K ? B##K : bs_prev; \
        float px = (E.x + (VK).x) - bse.x; \
        float py = (E.y + (VK).y) - bse.y; \
        float pz = (E.z + (VK).z) - bse.z; \
        float pw = (E.w + (VK).w) - bse.w; \
        float* o = out + 4 * (RJ); \
        bool priv = (hb##K || (src > 0)) && (RT); \
        if (priv) { \
            *(float4*)o = make_float4(px, py, pz, pw); \
        } else { \
            atomicAdd(o + 0, px); \
            atomicAdd(o + 1, py); \
            atomicAdd(o + 2, pz); \
            atomicAdd(o + 3, pw); \
        } \
    }
    EMIT(0, tl0, ra.x, V0, true)
    EMIT(1, tl1, ra.y, V1, true)
    EMIT(2, tl2, ra.z, V2, true)
    EMIT(3, tl3, ra.w, V3, true)
    EMIT(4, tl4, rb.x, V4, true)
    EMIT(5, tl5, rb.y, V5, true)
    EMIT(6, tl6, rb.z, V6, true)
    EMIT(7, tl7, rb.w, V7, rt7)
#undef EMIT
}

extern "C" void kernel_launch(void* const* d_in, const int* in_sizes, int n_in,
                              void* d_out, int out_size, void* d_ws, size_t ws_size,
                              hipStream_t stream) {
    const float* ts  = (const float*)d_in[0];
    const float* te  = (const float*)d_in[1];
    const float* sg  = (const float*)d_in[2];
    const float* hdr = (const float*)d_in[3];
    const int*   ri  = (const int*)d_in[4];
    const int S      = in_sizes[0];          // 4194304 = 2^22
    const int n_rays = out_size / 4;
    const int N1 = S >> 4;                   // 262144
    const int N2 = N1 >> 4;                  // 16384

    char* w = (char*)d_ws;
    auto alloc = [&](size_t bytes) { char* p = w; w += (bytes + 255) & ~255ULL; return p; };
    float* sdt = (float*)alloc((size_t)S * 4);
    float* s1  = (float*)alloc((size_t)N1 * 4);
    float* T1  = (float*)alloc((size_t)N2 * 4);

    k_bottom<<<dim3(N1 / TPB), dim3(TPB), 0, stream>>>(ts, te, sg, S, sdt, s1, T1,
                                                       (float4*)d_out, n_rays);
    k_render<<<dim3(S / (TPB * 8)), dim3(TPB), 0, stream>>>(ri, sdt, s1, T1, hdr,
                                                            S, (float*)d_out);
}